// Round 7
// baseline (352.278 us; speedup 1.0000x reference)
//
#include <hip/hip_runtime.h>
#include <stdint.h>

#define HNUM 24
#define DIMX 1536
#define NXT  2048
#define NCT  256
#define NTOT 2304
#define BB   2
#define NK   (DIMX / 64)   // 24 K-tiles

typedef __attribute__((ext_vector_type(8))) short bf16x8;
typedef __attribute__((ext_vector_type(8))) _Float16 f16x8;
typedef __attribute__((ext_vector_type(4))) _Float16 f16x4;
typedef __attribute__((ext_vector_type(2))) _Float16 f16x2;
typedef __attribute__((ext_vector_type(2))) __fp16 hp16x2;
typedef __attribute__((ext_vector_type(4))) float f32x4;
typedef __attribute__((ext_vector_type(16))) float f32x16;
typedef __attribute__((ext_vector_type(4))) unsigned short u16x4;

#define AS1 __attribute__((address_space(1)))
#define AS3 __attribute__((address_space(3)))

__device__ __forceinline__ void glds16(const void* g, void* l) {
  __builtin_amdgcn_global_load_lds((AS1 void*)(uintptr_t)g, (AS3 void*)l, 16, 0, 0);
}

__device__ __forceinline__ unsigned short f2bf(float f) {
  unsigned int u = __float_as_uint(f);
  u += 0x7FFFu + ((u >> 16) & 1u);   // RNE
  return (unsigned short)(u >> 16);
}

__device__ __forceinline__ f16x2 pkrtz(float a, float b) {
  hp16x2 r = __builtin_amdgcn_cvt_pkrtz(a, b);
  union { hp16x2 h; f16x2 f; } u;
  u.h = r;
  return u.f;
}

// Swizzled LDS fragment loads (rows of 64 elems = 128B; 16B-chunk pos XOR row&7).
__device__ __forceinline__ bf16x8 ldfragB(const unsigned short* S, int row, int cc) {
  return *(const bf16x8*)(S + row * 64 + ((cc ^ (row & 7)) << 3));
}
// V A-frag for 32x32x16: chunk c = w*2 + hi32 holds kv c*8..c*8+7, stored at
// c ^ (row&7). 64-lane pattern hits every 16B-pos with exactly 8 lanes ->
// uniform bank load (structural minimum, no conflict).
__device__ __forceinline__ f16x8 ldV32(const _Float16* S, int row, int w, int hi32) {
  int c = (w * 2 + hi32) ^ (row & 7);
  return *(const f16x8*)(S + row * 64 + c * 8);
}

// ------------------------------------------------------- fused cast kernel
struct CastDesc { const float* src; unsigned short* dst; int start4; };
struct CastArgs { CastDesc d[6]; int total4; };

__global__ __launch_bounds__(256) void cast_all(CastArgs a) {
  int i = blockIdx.x * 256 + threadIdx.x;
  if (i >= a.total4) return;
  int r = 0;
#pragma unroll
  for (int k = 1; k < 6; ++k) r += (i >= a.d[k].start4);
  int j = i - a.d[r].start4;
  float4 v = reinterpret_cast<const float4*>(a.d[r].src)[j];
  u16x4 o;
  o[0] = f2bf(v.x); o[1] = f2bf(v.y); o[2] = f2bf(v.z); o[3] = f2bf(v.w);
  reinterpret_cast<u16x4*>(a.d[r].dst)[j] = o;
}

// --------------------------------------------- 256x128 counted-vmcnt mainloop
__device__ __forceinline__ void gemm_mainloop256(
    const unsigned short* __restrict__ Ablk,   // 256 x DIMX
    const unsigned short* __restrict__ Wblk,   // 128 x DIMX
    unsigned short* As, unsigned short* Bs, f32x4 acc[4][4]) {
  const int tid  = threadIdx.x;
  const int lane = tid & 63;
  const int quad = lane >> 4, l16 = lane & 15;
  const int wave = tid >> 6;
  const int wm = (wave >> 1) * 64, wo = (wave & 1) * 64;

  auto stageA = [&](int kt, int buf, int i) {   // i in 0..3
    int c = i * 512 + tid;
    int row = c >> 3;                            // 0..255
    int kc = ((c & 7) ^ (row & 7)) << 3;
    glds16(Ablk + (size_t)row * DIMX + kt * 64 + kc, As + buf * (256 * 64) + c * 8);
  };
  auto stageB = [&](int kt, int buf, int i) {   // i in 0..1
    int c = i * 512 + tid;
    int row = c >> 3;                            // 0..127
    int kc = ((c & 7) ^ (row & 7)) << 3;
    glds16(Wblk + (size_t)row * DIMX + kt * 64 + kc, Bs + buf * (128 * 64) + c * 8);
  };

  stageA(0, 0, 0); stageA(0, 0, 1); stageA(0, 0, 2); stageA(0, 0, 3);
  stageB(0, 0, 0); stageB(0, 0, 1);
  stageA(1, 1, 0); stageA(1, 1, 1); stageA(1, 1, 2); stageA(1, 1, 3);
  stageB(1, 1, 0); stageB(1, 1, 1);
  asm volatile("s_waitcnt vmcnt(6)" ::: "memory");
  __builtin_amdgcn_s_barrier();

  int cur = 0;                                   // invariant: cur == kt % 3
  for (int kt = 0; kt < NK; ++kt) {
    const unsigned short* A_ = As + cur * (256 * 64);
    const unsigned short* B_ = Bs + cur * (128 * 64);
    const int stg = (cur == 0) ? 2 : cur - 1;
    const bool doStage = (kt + 2 < NK);
#pragma unroll
    for (int kk = 0; kk < 2; ++kk) {
      bf16x8 af[4], bfr[4];
#pragma unroll
      for (int mb = 0; mb < 4; ++mb)
        af[mb] = ldfragB(A_, wm + mb * 16 + l16, kk * 4 + quad);
#pragma unroll
      for (int ob = 0; ob < 4; ++ob)
        bfr[ob] = ldfragB(B_, wo + ob * 16 + l16, kk * 4 + quad);
      if (doStage) {
        if (kk == 0) { stageA(kt + 2, stg, 0); stageA(kt + 2, stg, 1); stageA(kt + 2, stg, 2); }
        else         { stageA(kt + 2, stg, 3); stageB(kt + 2, stg, 0); stageB(kt + 2, stg, 1); }
      }
      __builtin_amdgcn_s_setprio(1);
#pragma unroll
      for (int mb = 0; mb < 4; ++mb)
#pragma unroll
        for (int ob = 0; ob < 4; ++ob)
          acc[mb][ob] = __builtin_amdgcn_mfma_f32_16x16x32_bf16(
              af[mb], bfr[ob], acc[mb][ob], 0, 0, 0);
      __builtin_amdgcn_s_setprio(0);
    }
    if (doStage)          asm volatile("s_waitcnt vmcnt(6)" ::: "memory");
    else if (kt + 1 < NK) asm volatile("s_waitcnt vmcnt(0)" ::: "memory");
    __builtin_amdgcn_s_barrier();
    cur = (cur == 2) ? 0 : cur + 1;
  }
}

// --------------------------------------------------------------- QKV GEMM
__global__ __launch_bounds__(512, 2) void gemm_qkv(
    const unsigned short* __restrict__ xbf, const unsigned short* __restrict__ cbf,
    const unsigned short* __restrict__ Wx, const unsigned short* __restrict__ Wc,
    const float* __restrict__ bx_, const float* __restrict__ bc_,
    unsigned short* __restrict__ Qb, unsigned short* __restrict__ Kb,
    _Float16* __restrict__ VTf) {
  __shared__ unsigned short SA[3][256 * 64];   // 96 KB
  __shared__ unsigned short SB[3][128 * 64];   // 48 KB

  const int swz = ((int)blockIdx.x & 7) * (648 / 8) + ((int)blockIdx.x >> 3);
  const int bx = swz % 36;
  const int by = swz / 36;

  const bool isC = by >= 16;
  const int yloc = isC ? by - 16 : by;
  const int tokShift = isC ? 8 : 11;
  const int seqOff = isC ? NXT : 0;
  const unsigned short* A = (isC ? cbf : xbf) + (size_t)yloc * 256 * DIMX;
  const unsigned short* W = (isC ? Wc : Wx) + (size_t)bx * 128 * DIMX;
  const float* bias = isC ? bc_ : bx_;

  const f32x4 z4 = {0.f, 0.f, 0.f, 0.f};
  f32x4 acc[4][4];
#pragma unroll
  for (int i = 0; i < 4; ++i)
#pragma unroll
    for (int j = 0; j < 4; ++j) acc[i][j] = z4;

  gemm_mainloop256(A, W, &SA[0][0], &SB[0][0], acc);

  const int tid = threadIdx.x, lane = tid & 63, wave = tid >> 6;
  const int quad = lane >> 4, l16 = lane & 15;
  const int wm = (wave >> 1) * 64, wo = (wave & 1) * 64;
  const int s = bx / 12;
  const float QSC = 0.125f * 1.44269504088896340736f; // SCALE * log2(e)

  float bv[4];
#pragma unroll
  for (int ob = 0; ob < 4; ++ob)
    bv[ob] = bias[bx * 128 + wo + ob * 16 + l16];

  if (s < 2) {
#pragma unroll
    for (int ob = 0; ob < 4; ++ob) {
      int o = bx * 128 + wo + ob * 16 + l16;
      int rem = o - s * DIMX;
      int h = rem >> 6, d = rem & 63;
#pragma unroll
      for (int mb = 0; mb < 4; ++mb) {
#pragma unroll
        for (int r = 0; r < 4; ++r) {
          int m = yloc * 256 + wm + mb * 16 + quad * 4 + r;
          int b = m >> tokShift;
          int n = seqOff + (m & ((1 << tokShift) - 1));
          size_t bh = (size_t)b * HNUM + h;
          float v = acc[mb][ob][r] + bv[ob];
          if (s == 0) Qb[(bh * NTOT + n) * 64 + d] = f2bf(v * QSC);
          else        Kb[(bh * NTOT + n) * 64 + d] = f2bf(v);
        }
      }
    }
  } else {
    _Float16* Ts = (_Float16*)SA;
    __syncthreads();
#pragma unroll
    for (int ob = 0; ob < 4; ++ob) {
      int dloc = wo + ob * 16 + l16;            // 0..127
      int sw = (dloc & 31) << 3;
#pragma unroll
      for (int mb = 0; mb < 4; ++mb) {
        f16x4 pk;
#pragma unroll
        for (int r = 0; r < 4; ++r) pk[r] = (_Float16)(acc[mb][ob][r] + bv[ob]);
        int m0 = wm + mb * 16 + quad * 4;       // 0..255
        *(f16x4*)(Ts + dloc * 256 + (m0 ^ sw)) = pk;
      }
    }
    __syncthreads();
#pragma unroll
    for (int it = 0; it < 8; ++it) {
      int cth = it * 512 + tid;                 // 0..4095
      int d = cth >> 5;                         // 0..127
      int m0 = (cth & 31) << 3;                 // 0..248
      f16x8 val = *(const f16x8*)(Ts + d * 256 + (m0 ^ ((d & 31) << 3)));
      int dglob = (bx - 24) * 128 + d;
      int h = dglob >> 6, dd = dglob & 63;
      int M = yloc * 256 + m0;
      int b = M >> tokShift;
      int n = seqOff + (M & ((1 << tokShift) - 1));
      *(f16x8*)(VTf + ((size_t)(b * HNUM + h) * 64 + dd) * NTOT + n) = val;
    }
  }
}

// --------------------------------------------------------------- proj GEMM
__global__ __launch_bounds__(512, 2) void gemm_proj(
    const unsigned short* __restrict__ AX, const unsigned short* __restrict__ AC,
    const unsigned short* __restrict__ Wx, const unsigned short* __restrict__ Wc,
    const float* __restrict__ bx_, const float* __restrict__ bc_,
    float* __restrict__ out) {
  __shared__ unsigned short SA[3][256 * 64];
  __shared__ unsigned short SB[3][128 * 64];

  const int swz = ((int)blockIdx.x & 7) * (216 / 8) + ((int)blockIdx.x >> 3);
  const int bx = swz % 12;
  const int by = swz / 12;

  const bool isC = by >= 16;
  const int yloc = isC ? by - 16 : by;
  const unsigned short* A = (isC ? AC : AX) + (size_t)yloc * 256 * DIMX;
  const unsigned short* W = (isC ? Wc : Wx) + (size_t)bx * 128 * DIMX;
  const float* bias = isC ? bc_ : bx_;
  float* o_ = out + (isC ? (size_t)BB * NXT * DIMX : (size_t)0) +
              (size_t)yloc * 256 * DIMX;

  const f32x4 z4 = {0.f, 0.f, 0.f, 0.f};
  f32x4 acc[4][4];
#pragma unroll
  for (int i = 0; i < 4; ++i)
#pragma unroll
    for (int j = 0; j < 4; ++j) acc[i][j] = z4;

  gemm_mainloop256(A, W, &SA[0][0], &SB[0][0], acc);

  const int lane = threadIdx.x & 63, wave = threadIdx.x >> 6;
  const int quad = lane >> 4, l16 = lane & 15;
  const int wm = (wave >> 1) * 64, wo = (wave & 1) * 64;

#pragma unroll
  for (int ob = 0; ob < 4; ++ob) {
    int o = bx * 128 + wo + ob * 16 + l16;
    float bv = bias[o];
#pragma unroll
    for (int mb = 0; mb < 4; ++mb) {
#pragma unroll
      for (int r = 0; r < 4; ++r) {
        int m = wm + mb * 16 + quad * 4 + r;
        o_[(size_t)m * DIMX + o] = acc[mb][ob][r] + bv;
      }
    }
  }
}

// ------------------------------------------------------------ flash attention
// grid: (9 q-tiles of 256 rows, 48 b*h), 512 threads = 8 waves x 32 q-rows.
// PV via mfma_f32_32x32x16_f16 (8 MFMA/tile vs 16+8 of the 16x16x16 form,
// which measured ~25 pipe-cyc each for half the FLOPs).
// P relayout 16x16-C -> 32x32-B: dest lane q = l31, so the needed qb is the
// DEST lane's loQ for BOTH kv-halves. Each lane KEEPS pf[loQ] (its own
// kv-quad's slice) and SENDS pf[1-loQ] (what its lane^16 partner needs);
// exchange via __shfl_xor(.,16) (unambiguous semantics; ds_swizzle).
// Round-6 bug was feeding the exchange with pf[loQ] — wrong q for partner.
__global__ __launch_bounds__(512, 4) void flash_attn(
    const unsigned short* __restrict__ Qb, const unsigned short* __restrict__ Kb,
    const _Float16* __restrict__ Vf,
    unsigned short* __restrict__ AX, unsigned short* __restrict__ AC) {
  __shared__ unsigned short Ks[2][64 * 64];  // (kv, d) bf16, swizzled
  __shared__ _Float16      Vs[2][64 * 64];   // (d, kv) f16, linear-kv chunks ^row

  const int tid = threadIdx.x, lane = tid & 63, wave = tid >> 6;
  const int quad = lane >> 4, l16 = lane & 15;
  const int l31 = lane & 31, hi32 = lane >> 5;
  const int bh = blockIdx.y;
  const int qbase = blockIdx.x * 256 + wave * 32;

  bf16x8 qf[2][2];
#pragma unroll
  for (int qb = 0; qb < 2; ++qb)
#pragma unroll
    for (int kh = 0; kh < 2; ++kh)
      qf[qb][kh] = *(const bf16x8*)(
          Qb + ((size_t)bh * NTOT + qbase + qb * 16 + l16) * 64 + kh * 32 + quad * 8);

  const f32x4 z4 = {0.f, 0.f, 0.f, 0.f};
  f32x16 accT[2];                            // O^T 32x32 tiles: db in {0,1}
#pragma unroll
  for (int db = 0; db < 2; ++db)
#pragma unroll
    for (int r = 0; r < 16; ++r) accT[db][r] = 0.f;
  float lp[2] = {0.f, 0.f};

  const size_t kbase = (size_t)bh * NTOT * 64;
  const size_t vbase = (size_t)bh * 64 * NTOT;
  const f16x2 one2 = {(_Float16)1.f, (_Float16)1.f};

  // V staging: thread (row = tid>>3, chunk c = tid&7): one 16B global load of
  // kv = c*8..c*8+7, ds_write_b128 at chunk pos c ^ (row&7).
  const int srow = tid >> 3, scc = tid & 7;
  _Float16* const sdst0 = &Vs[0][0] + srow * 64 + ((scc ^ (srow & 7)) << 3);
  _Float16* const sdst1 = &Vs[1][0] + srow * 64 + ((scc ^ (srow & 7)) << 3);
  const _Float16* const vsrc = Vf + vbase + (size_t)srow * NTOT + scc * 8;

  f16x8 vstg;
  auto loadV = [&](int kt) { vstg = *(const f16x8*)(vsrc + (size_t)kt * 64); };
  auto writeV = [&](int kt) { *(f16x8*)((kt & 1) ? sdst1 : sdst0) = vstg; };
  auto stageK = [&](int kt) {
    const int kv0 = kt * 64;
    int row = tid >> 3;
    int kc = ((tid & 7) ^ (row & 7)) << 3;
    glds16(Kb + kbase + (size_t)(kv0 + row) * 64 + kc, &Ks[kt & 1][0] + tid * 8);
  };

  loadV(0);
  stageK(0);
  writeV(0);
  for (int kt = 0; kt < 36; ++kt) {
    __syncthreads();                          // publishes K(kt), V(kt)
    if (kt < 35) { loadV(kt + 1); stageK(kt + 1); }
    const unsigned short* K_ = &Ks[kt & 1][0];
    const _Float16*       V_ = &Vs[kt & 1][0];

    // S^T = K * Q^T : rows kv (mb*16+quad*4+r), cols q (l16)
    f32x4 st[2][4];
#pragma unroll
    for (int qb = 0; qb < 2; ++qb)
#pragma unroll
      for (int mb = 0; mb < 4; ++mb) st[qb][mb] = z4;
    __builtin_amdgcn_s_setprio(1);
#pragma unroll
    for (int kh = 0; kh < 2; ++kh) {
#pragma unroll
      for (int mb = 0; mb < 4; ++mb) {
        bf16x8 kf = ldfragB(K_, mb * 16 + l16, kh * 4 + quad);
#pragma unroll
        for (int qb = 0; qb < 2; ++qb)
          st[qb][mb] = __builtin_amdgcn_mfma_f32_16x16x32_bf16(
              kf, qf[qb][kh], st[qb][mb], 0, 0, 0);
      }
    }
    __builtin_amdgcn_s_setprio(0);

    // P^T = exp2(S^T) packed f16; l via fdot2 (VALU)
    f16x4 pf[2][4];
#pragma unroll
    for (int qb = 0; qb < 2; ++qb) {
#pragma unroll
      for (int mb = 0; mb < 4; ++mb) {
        float p0 = __builtin_amdgcn_exp2f(st[qb][mb][0]);
        float p1 = __builtin_amdgcn_exp2f(st[qb][mb][1]);
        float p2 = __builtin_amdgcn_exp2f(st[qb][mb][2]);
        float p3 = __builtin_amdgcn_exp2f(st[qb][mb][3]);
        f16x2 lo = pkrtz(p0, p1);
        f16x2 hi = pkrtz(p2, p3);
        lp[qb] = __builtin_amdgcn_fdot2(lo, one2, lp[qb], false);
        lp[qb] = __builtin_amdgcn_fdot2(hi, one2, lp[qb], false);
        f16x4 pk = {lo[0], lo[1], hi[0], hi[1]};
        pf[qb][mb] = pk;
      }
    }

    // B-frag assembly: B[k = 8*hi32 + j8][q = l31], window mb.
    // j8 0..3 <- even kv-quad (2*hi32), j8 4..7 <- odd (2*hi32+1).
    // keep = pf[loQ] (own kv-quad slice, own q); send = pf[1-loQ]
    // (partner's q, own kv-quad slice); rec = partner's send (own q,
    // partner's kv-quad slice). Even lane: low = keep, high = rec.
    // Odd lane: low = rec, high = keep.
    f16x8 bfr[4];
    const bool loQ = (lane & 16) != 0;
#pragma unroll
    for (int mb = 0; mb < 4; ++mb) {
      union { f16x4 v; unsigned int u[2]; } pk_, ps_;
      pk_.v = loQ ? pf[1][mb] : pf[0][mb];   // keep
      ps_.v = loQ ? pf[0][mb] : pf[1][mb];   // send
      unsigned int rec0 = (unsigned int)__shfl_xor((int)ps_.u[0], 16);
      unsigned int rec1 = (unsigned int)__shfl_xor((int)ps_.u[1], 16);
      union { f16x8 v; unsigned int u[4]; } bb;
      bb.u[0] = loQ ? rec0 : pk_.u[0];
      bb.u[1] = loQ ? rec1 : pk_.u[1];
      bb.u[2] = loQ ? pk_.u[0] : rec0;
      bb.u[3] = loQ ? pk_.u[1] : rec1;
      bfr[mb] = bb.v;
    }

    if (kt < 35) writeV(kt + 1);              // vstg arrived during QK+exp

    // O^T += V^T * P^T : 32x32x16 f16, A = V^T (rows d = db*32 + l31)
    __builtin_amdgcn_s_setprio(1);
#pragma unroll
    for (int db = 0; db < 2; ++db) {
      const int vrow = db * 32 + l31;
#pragma unroll
      for (int w = 0; w < 4; ++w) {
        f16x8 va = ldV32(V_, vrow, w, hi32);
        accT[db] = __builtin_amdgcn_mfma_f32_32x32x16_f16(
            va, bfr[w], accT[db], 0, 0, 0);
      }
    }
    __builtin_amdgcn_s_setprio(0);
  }

  // l reduction across quads (kv-partials) -> 2 shuffles; per-lane q select
  float inv[2];
#pragma unroll
  for (int qb = 0; qb < 2; ++qb) {
    float l = lp[qb];
    l += __shfl_xor(l, 16);
    l += __shfl_xor(l, 32);
    inv[qb] = __frcp_rn(l);
  }
  const float invSel = (lane & 16) ? inv[1] : inv[0];

  // epilogue: 32x32 C layout: col q = l31, row d32 = 8*rq + 4*hi32 + r
  const int b = bh / HNUM, h = bh - b * HNUM;
  {
    int n = qbase + l31;
#pragma unroll
    for (int db = 0; db < 2; ++db) {
#pragma unroll
      for (int rq = 0; rq < 4; ++rq) {
        u16x4 o;
#pragma unroll
        for (int r = 0; r < 4; ++r) o[r] = f2bf(accT[db][rq * 4 + r] * invSel);
        int col = h * 64 + db * 32 + rq * 8 + hi32 * 4;
        if (n < NXT)
          *(u16x4*)(AX + ((size_t)b * NXT + n) * DIMX + col) = o;
        else
          *(u16x4*)(AC + ((size_t)b * NCT + (n - NXT)) * DIMX + col) = o;
      }
    }
  }
}

// ------------------------------------------------------------------- launcher
extern "C" void kernel_launch(void* const* d_in, const int* in_sizes, int n_in,
                              void* d_out, int out_size, void* d_ws, size_t ws_size,
                              hipStream_t stream) {
  const float* x       = (const float*)d_in[0];
  const float* c       = (const float*)d_in[1];
  const float* Wqkv_x  = (const float*)d_in[2];
  const float* bqkv_x  = (const float*)d_in[3];
  const float* Wqkv_c  = (const float*)d_in[4];
  const float* bqkv_c  = (const float*)d_in[5];
  const float* Wproj_x = (const float*)d_in[6];
  const float* bproj_x = (const float*)d_in[7];
  const float* Wproj_c = (const float*)d_in[8];
  const float* bproj_c = (const float*)d_in[9];
  float* out = (float*)d_out;

  char* ws = (char*)d_ws;
  size_t off = 0;
  auto alloc = [&](size_t nelem) {
    unsigned short* p = (unsigned short*)(ws + off);
    off += nelem * 2;
    return p;
  };
  unsigned short* xbf  = alloc((size_t)BB * NXT * DIMX);
  unsigned short* cbf  = alloc((size_t)BB * NCT * DIMX);
  unsigned short* wqx  = alloc((size_t)3 * DIMX * DIMX);
  unsigned short* wqc  = alloc((size_t)3 * DIMX * DIMX);
  unsigned short* wpx  = alloc((size_t)DIMX * DIMX);
  unsigned short* wpc  = alloc((size_t)DIMX * DIMX);
  unsigned short* Qb   = alloc((size_t)BB * HNUM * NTOT * 64);
  unsigned short* Kb   = alloc((size_t)BB * HNUM * NTOT * 64);
  _Float16*       VTf  = (_Float16*)alloc((size_t)BB * HNUM * NTOT * 64);
  unsigned short* AX   = alloc((size_t)BB * NXT * DIMX);
  unsigned short* AC   = alloc((size_t)BB * NCT * DIMX);

  CastArgs ca;
  const float* srcs[6] = {x, c, Wqkv_x, Wqkv_c, Wproj_x, Wproj_c};
  unsigned short* dsts[6] = {xbf, cbf, wqx, wqc, wpx, wpc};
  size_t ns[6] = {(size_t)BB * NXT * DIMX, (size_t)BB * NCT * DIMX,
                  (size_t)3 * DIMX * DIMX, (size_t)3 * DIMX * DIMX,
                  (size_t)DIMX * DIMX, (size_t)DIMX * DIMX};
  int acc4 = 0;
  for (int i = 0; i < 6; ++i) {
    ca.d[i].src = srcs[i];
    ca.d[i].dst = dsts[i];
    ca.d[i].start4 = acc4;
    acc4 += (int)(ns[i] / 4);
  }
  ca.total4 = acc4;
  cast_all<<<dim3((acc4 + 255) / 256), dim3(256), 0, stream>>>(ca);

  gemm_qkv<<<dim3(648), dim3(512), 0, stream>>>(xbf, cbf, wqx, wqc,
                                                bqkv_x, bqkv_c, Qb, Kb, VTf);

  flash_attn<<<dim3(9, 48), dim3(512), 0, stream>>>(Qb, Kb, VTf, AX, AC);

  gemm_proj<<<dim3(216), dim3(512), 0, stream>>>(AX, AC, wpx, wpc,
                                                 bproj_x, bproj_c, out);
}

// Round 8
// 337.392 us; speedup vs baseline: 1.0441x; 1.0441x over previous
//
#include <hip/hip_runtime.h>
#include <stdint.h>

#define HNUM 24
#define DIMX 1536
#define NXT  2048
#define NCT  256
#define NTOT 2304
#define BB   2
#define NK   (DIMX / 64)   // 24 K-tiles

typedef __attribute__((ext_vector_type(8))) short bf16x8;
typedef __attribute__((ext_vector_type(8))) _Float16 f16x8;
typedef __attribute__((ext_vector_type(4))) _Float16 f16x4;
typedef __attribute__((ext_vector_type(2))) _Float16 f16x2;
typedef __attribute__((ext_vector_type(2))) __fp16 hp16x2;
typedef __attribute__((ext_vector_type(4))) float f32x4;
typedef __attribute__((ext_vector_type(16))) float f32x16;
typedef __attribute__((ext_vector_type(4))) unsigned short u16x4;

#define AS1 __attribute__((address_space(1)))
#define AS3 __attribute__((address_space(3)))

__device__ __forceinline__ void glds16(const void* g, void* l) {
  __builtin_amdgcn_global_load_lds((AS1 void*)(uintptr_t)g, (AS3 void*)l, 16, 0, 0);
}

__device__ __forceinline__ unsigned short f2bf(float f) {
  unsigned int u = __float_as_uint(f);
  u += 0x7FFFu + ((u >> 16) & 1u);   // RNE
  return (unsigned short)(u >> 16);
}

__device__ __forceinline__ f16x2 pkrtz(float a, float b) {
  hp16x2 r = __builtin_amdgcn_cvt_pkrtz(a, b);
  union { hp16x2 h; f16x2 f; } u;
  u.h = r;
  return u.f;
}

// Swizzled LDS fragment loads (rows of 64 elems = 128B; 16B-chunk pos XOR row&7).
__device__ __forceinline__ bf16x8 ldfragB(const unsigned short* S, int row, int cc) {
  return *(const bf16x8*)(S + row * 64 + ((cc ^ (row & 7)) << 3));
}
// V A-frag for 32x32x16: chunk c = w*2 + hi32 holds kv c*8..c*8+7, stored at
// c ^ (row&7). Uniform bank load across the wave.
__device__ __forceinline__ f16x8 ldV32(const _Float16* S, int row, int w, int hi32) {
  int c = (w * 2 + hi32) ^ (row & 7);
  return *(const f16x8*)(S + row * 64 + c * 8);
}

// ------------------------------------------------------- fused cast kernel
struct CastDesc { const float* src; unsigned short* dst; int start4; };
struct CastArgs { CastDesc d[6]; int total4; };

__global__ __launch_bounds__(256) void cast_all(CastArgs a) {
  int i = blockIdx.x * 256 + threadIdx.x;
  if (i >= a.total4) return;
  int r = 0;
#pragma unroll
  for (int k = 1; k < 6; ++k) r += (i >= a.d[k].start4);
  int j = i - a.d[r].start4;
  float4 v = reinterpret_cast<const float4*>(a.d[r].src)[j];
  u16x4 o;
  o[0] = f2bf(v.x); o[1] = f2bf(v.y); o[2] = f2bf(v.z); o[3] = f2bf(v.w);
  reinterpret_cast<u16x4*>(a.d[r].dst)[j] = o;
}

// --------------------------------------------- 256x128 counted-vmcnt mainloop
__device__ __forceinline__ void gemm_mainloop256(
    const unsigned short* __restrict__ Ablk,   // 256 x DIMX
    const unsigned short* __restrict__ Wblk,   // 128 x DIMX
    unsigned short* As, unsigned short* Bs, f32x4 acc[4][4]) {
  const int tid  = threadIdx.x;
  const int lane = tid & 63;
  const int quad = lane >> 4, l16 = lane & 15;
  const int wave = tid >> 6;
  const int wm = (wave >> 1) * 64, wo = (wave & 1) * 64;

  auto stageA = [&](int kt, int buf, int i) {   // i in 0..3
    int c = i * 512 + tid;
    int row = c >> 3;                            // 0..255
    int kc = ((c & 7) ^ (row & 7)) << 3;
    glds16(Ablk + (size_t)row * DIMX + kt * 64 + kc, As + buf * (256 * 64) + c * 8);
  };
  auto stageB = [&](int kt, int buf, int i) {   // i in 0..1
    int c = i * 512 + tid;
    int row = c >> 3;                            // 0..127
    int kc = ((c & 7) ^ (row & 7)) << 3;
    glds16(Wblk + (size_t)row * DIMX + kt * 64 + kc, Bs + buf * (128 * 64) + c * 8);
  };

  stageA(0, 0, 0); stageA(0, 0, 1); stageA(0, 0, 2); stageA(0, 0, 3);
  stageB(0, 0, 0); stageB(0, 0, 1);
  stageA(1, 1, 0); stageA(1, 1, 1); stageA(1, 1, 2); stageA(1, 1, 3);
  stageB(1, 1, 0); stageB(1, 1, 1);
  asm volatile("s_waitcnt vmcnt(6)" ::: "memory");
  __builtin_amdgcn_s_barrier();

  int cur = 0;                                   // invariant: cur == kt % 3
  for (int kt = 0; kt < NK; ++kt) {
    const unsigned short* A_ = As + cur * (256 * 64);
    const unsigned short* B_ = Bs + cur * (128 * 64);
    const int stg = (cur == 0) ? 2 : cur - 1;
    const bool doStage = (kt + 2 < NK);
#pragma unroll
    for (int kk = 0; kk < 2; ++kk) {
      bf16x8 af[4], bfr[4];
#pragma unroll
      for (int mb = 0; mb < 4; ++mb)
        af[mb] = ldfragB(A_, wm + mb * 16 + l16, kk * 4 + quad);
#pragma unroll
      for (int ob = 0; ob < 4; ++ob)
        bfr[ob] = ldfragB(B_, wo + ob * 16 + l16, kk * 4 + quad);
      if (doStage) {
        if (kk == 0) { stageA(kt + 2, stg, 0); stageA(kt + 2, stg, 1); stageA(kt + 2, stg, 2); }
        else         { stageA(kt + 2, stg, 3); stageB(kt + 2, stg, 0); stageB(kt + 2, stg, 1); }
      }
      __builtin_amdgcn_s_setprio(1);
#pragma unroll
      for (int mb = 0; mb < 4; ++mb)
#pragma unroll
        for (int ob = 0; ob < 4; ++ob)
          acc[mb][ob] = __builtin_amdgcn_mfma_f32_16x16x32_bf16(
              af[mb], bfr[ob], acc[mb][ob], 0, 0, 0);
      __builtin_amdgcn_s_setprio(0);
    }
    if (doStage)          asm volatile("s_waitcnt vmcnt(6)" ::: "memory");
    else if (kt + 1 < NK) asm volatile("s_waitcnt vmcnt(0)" ::: "memory");
    __builtin_amdgcn_s_barrier();
    cur = (cur == 2) ? 0 : cur + 1;
  }
}

// --------------------------------------------------------------- QKV GEMM
__global__ __launch_bounds__(512, 2) void gemm_qkv(
    const unsigned short* __restrict__ xbf, const unsigned short* __restrict__ cbf,
    const unsigned short* __restrict__ Wx, const unsigned short* __restrict__ Wc,
    const float* __restrict__ bx_, const float* __restrict__ bc_,
    unsigned short* __restrict__ Qb, unsigned short* __restrict__ Kb,
    _Float16* __restrict__ VTf) {
  __shared__ unsigned short SA[3][256 * 64];   // 96 KB
  __shared__ unsigned short SB[3][128 * 64];   // 48 KB

  const int swz = ((int)blockIdx.x & 7) * (648 / 8) + ((int)blockIdx.x >> 3);
  const int bx = swz % 36;
  const int by = swz / 36;

  const bool isC = by >= 16;
  const int yloc = isC ? by - 16 : by;
  const int tokShift = isC ? 8 : 11;
  const int seqOff = isC ? NXT : 0;
  const unsigned short* A = (isC ? cbf : xbf) + (size_t)yloc * 256 * DIMX;
  const unsigned short* W = (isC ? Wc : Wx) + (size_t)bx * 128 * DIMX;
  const float* bias = isC ? bc_ : bx_;

  const f32x4 z4 = {0.f, 0.f, 0.f, 0.f};
  f32x4 acc[4][4];
#pragma unroll
  for (int i = 0; i < 4; ++i)
#pragma unroll
    for (int j = 0; j < 4; ++j) acc[i][j] = z4;

  gemm_mainloop256(A, W, &SA[0][0], &SB[0][0], acc);

  const int tid = threadIdx.x, lane = tid & 63, wave = tid >> 6;
  const int quad = lane >> 4, l16 = lane & 15;
  const int wm = (wave >> 1) * 64, wo = (wave & 1) * 64;
  const int s = bx / 12;
  const float QSC = 0.125f * 1.44269504088896340736f; // SCALE * log2(e)

  float bv[4];
#pragma unroll
  for (int ob = 0; ob < 4; ++ob)
    bv[ob] = bias[bx * 128 + wo + ob * 16 + l16];

  if (s < 2) {
#pragma unroll
    for (int ob = 0; ob < 4; ++ob) {
      int o = bx * 128 + wo + ob * 16 + l16;
      int rem = o - s * DIMX;
      int h = rem >> 6, d = rem & 63;
#pragma unroll
      for (int mb = 0; mb < 4; ++mb) {
#pragma unroll
        for (int r = 0; r < 4; ++r) {
          int m = yloc * 256 + wm + mb * 16 + quad * 4 + r;
          int b = m >> tokShift;
          int n = seqOff + (m & ((1 << tokShift) - 1));
          size_t bh = (size_t)b * HNUM + h;
          float v = acc[mb][ob][r] + bv[ob];
          if (s == 0) Qb[(bh * NTOT + n) * 64 + d] = f2bf(v * QSC);
          else        Kb[(bh * NTOT + n) * 64 + d] = f2bf(v);
        }
      }
    }
  } else {
    _Float16* Ts = (_Float16*)SA;
    __syncthreads();
#pragma unroll
    for (int ob = 0; ob < 4; ++ob) {
      int dloc = wo + ob * 16 + l16;            // 0..127
      int sw = (dloc & 31) << 3;
#pragma unroll
      for (int mb = 0; mb < 4; ++mb) {
        f16x4 pk;
#pragma unroll
        for (int r = 0; r < 4; ++r) pk[r] = (_Float16)(acc[mb][ob][r] + bv[ob]);
        int m0 = wm + mb * 16 + quad * 4;       // 0..255
        *(f16x4*)(Ts + dloc * 256 + (m0 ^ sw)) = pk;
      }
    }
    __syncthreads();
#pragma unroll
    for (int it = 0; it < 8; ++it) {
      int cth = it * 512 + tid;                 // 0..4095
      int d = cth >> 5;                         // 0..127
      int m0 = (cth & 31) << 3;                 // 0..248
      f16x8 val = *(const f16x8*)(Ts + d * 256 + (m0 ^ ((d & 31) << 3)));
      int dglob = (bx - 24) * 128 + d;
      int h = dglob >> 6, dd = dglob & 63;
      int M = yloc * 256 + m0;
      int b = M >> tokShift;
      int n = seqOff + (M & ((1 << tokShift) - 1));
      *(f16x8*)(VTf + ((size_t)(b * HNUM + h) * 64 + dd) * NTOT + n) = val;
    }
  }
}

// --------------------------------------------------------------- proj GEMM
__global__ __launch_bounds__(512, 2) void gemm_proj(
    const unsigned short* __restrict__ AX, const unsigned short* __restrict__ AC,
    const unsigned short* __restrict__ Wx, const unsigned short* __restrict__ Wc,
    const float* __restrict__ bx_, const float* __restrict__ bc_,
    float* __restrict__ out) {
  __shared__ unsigned short SA[3][256 * 64];
  __shared__ unsigned short SB[3][128 * 64];

  const int swz = ((int)blockIdx.x & 7) * (216 / 8) + ((int)blockIdx.x >> 3);
  const int bx = swz % 12;
  const int by = swz / 12;

  const bool isC = by >= 16;
  const int yloc = isC ? by - 16 : by;
  const unsigned short* A = (isC ? AC : AX) + (size_t)yloc * 256 * DIMX;
  const unsigned short* W = (isC ? Wc : Wx) + (size_t)bx * 128 * DIMX;
  const float* bias = isC ? bc_ : bx_;
  float* o_ = out + (isC ? (size_t)BB * NXT * DIMX : (size_t)0) +
              (size_t)yloc * 256 * DIMX;

  const f32x4 z4 = {0.f, 0.f, 0.f, 0.f};
  f32x4 acc[4][4];
#pragma unroll
  for (int i = 0; i < 4; ++i)
#pragma unroll
    for (int j = 0; j < 4; ++j) acc[i][j] = z4;

  gemm_mainloop256(A, W, &SA[0][0], &SB[0][0], acc);

  const int lane = threadIdx.x & 63, wave = threadIdx.x >> 6;
  const int quad = lane >> 4, l16 = lane & 15;
  const int wm = (wave >> 1) * 64, wo = (wave & 1) * 64;

#pragma unroll
  for (int ob = 0; ob < 4; ++ob) {
    int o = bx * 128 + wo + ob * 16 + l16;
    float bv = bias[o];
#pragma unroll
    for (int mb = 0; mb < 4; ++mb) {
#pragma unroll
      for (int r = 0; r < 4; ++r) {
        int m = wm + mb * 16 + quad * 4 + r;
        o_[(size_t)m * DIMX + o] = acc[mb][ob][r] + bv;
      }
    }
  }
}

// ------------------------------------------------------------ flash attention
// grid: (9 q-tiles of 256 rows, 48 b*h), 512 threads = 8 waves x 32 q-rows.
// Convoy-break: barrier every TWO tiles (4 K/V LDS buffers, 64KB). Round 7
// proved the per-tile barrier was the residual: MFMA-pipe time halved (util
// 48->28) with ZERO dur change, and no pipe >40% while their sum is >100% --
// waves were phase-locked (all-QK / all-exp / all-PV). A 2-tile barrier
// interval lets waves drift ~1800cyc so one wave's exp overlaps another's
// MFMA. Buffer writes (kt+2,kt+3)&3 are disjoint from reads (kt,kt+1)&3
// under maximal drift.
__global__ __launch_bounds__(512, 4) void flash_attn(
    const unsigned short* __restrict__ Qb, const unsigned short* __restrict__ Kb,
    const _Float16* __restrict__ Vf,
    unsigned short* __restrict__ AX, unsigned short* __restrict__ AC) {
  __shared__ unsigned short Ks[4][64 * 64];  // (kv, d) bf16, swizzled
  __shared__ _Float16      Vs[4][64 * 64];   // (d, kv) f16, linear-kv chunks ^row

  const int tid = threadIdx.x, lane = tid & 63, wave = tid >> 6;
  const int quad = lane >> 4, l16 = lane & 15;
  const int l31 = lane & 31, hi32 = lane >> 5;
  const int bh = blockIdx.y;
  const int qbase = blockIdx.x * 256 + wave * 32;

  bf16x8 qf[2][2];
#pragma unroll
  for (int qb = 0; qb < 2; ++qb)
#pragma unroll
    for (int kh = 0; kh < 2; ++kh)
      qf[qb][kh] = *(const bf16x8*)(
          Qb + ((size_t)bh * NTOT + qbase + qb * 16 + l16) * 64 + kh * 32 + quad * 8);

  const f32x4 z4 = {0.f, 0.f, 0.f, 0.f};
  f32x16 accT[2];                            // O^T 32x32 tiles: db in {0,1}
#pragma unroll
  for (int db = 0; db < 2; ++db)
#pragma unroll
    for (int r = 0; r < 16; ++r) accT[db][r] = 0.f;
  float lp[2] = {0.f, 0.f};

  const size_t kbase = (size_t)bh * NTOT * 64;
  const size_t vbase = (size_t)bh * 64 * NTOT;
  const f16x2 one2 = {(_Float16)1.f, (_Float16)1.f};

  // V staging: thread (row = tid>>3, chunk c = tid&7): one 16B global load of
  // kv = c*8..c*8+7, ds_write_b128 at chunk pos c ^ (row&7).
  const int srow = tid >> 3, scc = tid & 7;
  const int soff = srow * 64 + ((scc ^ (srow & 7)) << 3);
  const _Float16* const vsrc = Vf + vbase + (size_t)srow * NTOT + scc * 8;

  f16x8 vstgA, vstgB;                        // in-flight V regs, tiles kt+2/kt+3
  auto loadVA  = [&](int kt) { vstgA = *(const f16x8*)(vsrc + (size_t)kt * 64); };
  auto loadVB  = [&](int kt) { vstgB = *(const f16x8*)(vsrc + (size_t)kt * 64); };
  auto writeVA = [&](int kt) { *(f16x8*)(&Vs[kt & 3][0] + soff) = vstgA; };
  auto writeVB = [&](int kt) { *(f16x8*)(&Vs[kt & 3][0] + soff) = vstgB; };
  auto stageK  = [&](int kt) {
    const int kv0 = kt * 64;
    int row = tid >> 3;
    int kc = ((tid & 7) ^ (row & 7)) << 3;
    glds16(Kb + kbase + (size_t)(kv0 + row) * 64 + kc, &Ks[kt & 3][0] + tid * 8);
  };

  auto computeTile = [&](int kt) {
    const unsigned short* K_ = &Ks[kt & 3][0];
    const _Float16*       V_ = &Vs[kt & 3][0];

    // S^T = K * Q^T : rows kv (mb*16+quad*4+r), cols q (l16)
    f32x4 st[2][4];
#pragma unroll
    for (int qb = 0; qb < 2; ++qb)
#pragma unroll
      for (int mb = 0; mb < 4; ++mb) st[qb][mb] = z4;
    __builtin_amdgcn_s_setprio(1);
#pragma unroll
    for (int kh = 0; kh < 2; ++kh) {
#pragma unroll
      for (int mb = 0; mb < 4; ++mb) {
        bf16x8 kf = ldfragB(K_, mb * 16 + l16, kh * 4 + quad);
#pragma unroll
        for (int qb = 0; qb < 2; ++qb)
          st[qb][mb] = __builtin_amdgcn_mfma_f32_16x16x32_bf16(
              kf, qf[qb][kh], st[qb][mb], 0, 0, 0);
      }
    }
    __builtin_amdgcn_s_setprio(0);

    // P^T = exp2(S^T) packed f16; l via fdot2 (VALU)
    f16x4 pf[2][4];
#pragma unroll
    for (int qb = 0; qb < 2; ++qb) {
#pragma unroll
      for (int mb = 0; mb < 4; ++mb) {
        float p0 = __builtin_amdgcn_exp2f(st[qb][mb][0]);
        float p1 = __builtin_amdgcn_exp2f(st[qb][mb][1]);
        float p2 = __builtin_amdgcn_exp2f(st[qb][mb][2]);
        float p3 = __builtin_amdgcn_exp2f(st[qb][mb][3]);
        f16x2 lo = pkrtz(p0, p1);
        f16x2 hi = pkrtz(p2, p3);
        lp[qb] = __builtin_amdgcn_fdot2(lo, one2, lp[qb], false);
        lp[qb] = __builtin_amdgcn_fdot2(hi, one2, lp[qb], false);
        f16x4 pk = {lo[0], lo[1], hi[0], hi[1]};
        pf[qb][mb] = pk;
      }
    }

    // B-frag assembly: B[k = 8*hi32 + j8][q = l31]; keep pf[loQ], send
    // pf[1-loQ] across lane^16 (partner's q, own kv-quad slice).
    f16x8 bfr[4];
    const bool loQ = (lane & 16) != 0;
#pragma unroll
    for (int mb = 0; mb < 4; ++mb) {
      union { f16x4 v; unsigned int u[2]; } pk_, ps_;
      pk_.v = loQ ? pf[1][mb] : pf[0][mb];   // keep
      ps_.v = loQ ? pf[0][mb] : pf[1][mb];   // send
      unsigned int rec0 = (unsigned int)__shfl_xor((int)ps_.u[0], 16);
      unsigned int rec1 = (unsigned int)__shfl_xor((int)ps_.u[1], 16);
      union { f16x8 v; unsigned int u[4]; } bb;
      bb.u[0] = loQ ? rec0 : pk_.u[0];
      bb.u[1] = loQ ? rec1 : pk_.u[1];
      bb.u[2] = loQ ? pk_.u[0] : rec0;
      bb.u[3] = loQ ? pk_.u[1] : rec1;
      bfr[mb] = bb.v;
    }

    // O^T += V^T * P^T : 32x32x16 f16, A = V^T (rows d = db*32 + l31)
    __builtin_amdgcn_s_setprio(1);
#pragma unroll
    for (int db = 0; db < 2; ++db) {
      const int vrow = db * 32 + l31;
#pragma unroll
      for (int w = 0; w < 4; ++w) {
        f16x8 va = ldV32(V_, vrow, w, hi32);
        accT[db] = __builtin_amdgcn_mfma_f32_32x32x16_f16(
            va, bfr[w], accT[db], 0, 0, 0);
      }
    }
    __builtin_amdgcn_s_setprio(0);
  };

  loadVA(0); loadVB(1);
  stageK(0); stageK(1);
  writeVA(0); writeVB(1);
  __syncthreads();                            // tiles 0,1 resident
  for (int kt = 0; kt < 36; kt += 2) {
    const bool more = (kt + 2 < 36);
    if (more) { loadVA(kt + 2); loadVB(kt + 3); stageK(kt + 2); stageK(kt + 3); }
    computeTile(kt);
    if (more) { writeVA(kt + 2); writeVB(kt + 3); }  // V regs arrived under QK/exp
    computeTile(kt + 1);
    __syncthreads();                          // publishes K/V(kt+2, kt+3)
  }

  // l reduction across quads (kv-partials) -> 2 shuffles; per-lane q select
  float inv[2];
#pragma unroll
  for (int qb = 0; qb < 2; ++qb) {
    float l = lp[qb];
    l += __shfl_xor(l, 16);
    l += __shfl_xor(l, 32);
    inv[qb] = __frcp_rn(l);
  }
  const float invSel = (lane & 16) ? inv[1] : inv[0];

  // epilogue: 32x32 C layout: col q = l31, row d32 = 8*rq + 4*hi32 + r
  const int b = bh / HNUM, h = bh - b * HNUM;
  {
    int n = qbase + l31;
#pragma unroll
    for (int db = 0; db < 2; ++db) {
#pragma unroll
      for (int rq = 0; rq < 4; ++rq) {
        u16x4 o;
#pragma unroll
        for (int r = 0; r < 4; ++r) o[r] = f2bf(accT[db][rq * 4 + r] * invSel);
        int col = h * 64 + db * 32 + rq * 8 + hi32 * 4;
        if (n < NXT)
          *(u16x4*)(AX + ((size_t)b * NXT + n) * DIMX + col) = o;
        else
          *(u16x4*)(AC + ((size_t)b * NCT + (n - NXT)) * DIMX + col) = o;
      }
    }
  }
}

// ------------------------------------------------------------------- launcher
extern "C" void kernel_launch(void* const* d_in, const int* in_sizes, int n_in,
                              void* d_out, int out_size, void* d_ws, size_t ws_size,
                              hipStream_t stream) {
  const float* x       = (const float*)d_in[0];
  const float* c       = (const float*)d_in[1];
  const float* Wqkv_x  = (const float*)d_in[2];
  const float* bqkv_x  = (const float*)d_in[3];
  const float* Wqkv_c  = (const float*)d_in[4];
  const float* bqkv_c  = (const float*)d_in[5];
  const float* Wproj_x = (const float*)d_in[6];
  const float* bproj_x = (const float*)d_in[7];
  const float* Wproj_c = (const float*)d_in[8];
  const float* bproj_c = (const float*)d_in[9];
  float* out = (float*)d_out;

  char* ws = (char*)d_ws;
  size_t off = 0;
  auto alloc = [&](size_t nelem) {
    unsigned short* p = (unsigned short*)(ws + off);
    off += nelem * 2;
    return p;
  };
  unsigned short* xbf  = alloc((size_t)BB * NXT * DIMX);
  unsigned short* cbf  = alloc((size_t)BB * NCT * DIMX);
  unsigned short* wqx  = alloc((size_t)3 * DIMX * DIMX);
  unsigned short* wqc  = alloc((size_t)3 * DIMX * DIMX);
  unsigned short* wpx  = alloc((size_t)DIMX * DIMX);
  unsigned short* wpc  = alloc((size_t)DIMX * DIMX);
  unsigned short* Qb   = alloc((size_t)BB * HNUM * NTOT * 64);
  unsigned short* Kb   = alloc((size_t)BB * HNUM * NTOT * 64);
  _Float16*       VTf  = (_Float16*)alloc((size_t)BB * HNUM * NTOT * 64);
  unsigned short* AX   = alloc((size_t)BB * NXT * DIMX);
  unsigned short* AC   = alloc((size_t)BB * NCT * DIMX);

  CastArgs ca;
  const float* srcs[6] = {x, c, Wqkv_x, Wqkv_c, Wproj_x, Wproj_c};
  unsigned short* dsts[6] = {xbf, cbf, wqx, wqc, wpx, wpc};
  size_t ns[6] = {(size_t)BB * NXT * DIMX, (size_t)BB * NCT * DIMX,
                  (size_t)3 * DIMX * DIMX, (size_t)3 * DIMX * DIMX,
                  (size_t)DIMX * DIMX, (size_t)DIMX * DIMX};
  int acc4 = 0;
  for (int i = 0; i < 6; ++i) {
    ca.d[i].src = srcs[i];
    ca.d[i].dst = dsts[i];
    ca.d[i].start4 = acc4;
    acc4 += (int)(ns[i] / 4);
  }
  ca.total4 = acc4;
  cast_all<<<dim3((acc4 + 255) / 256), dim3(256), 0, stream>>>(ca);

  gemm_qkv<<<dim3(648), dim3(512), 0, stream>>>(xbf, cbf, wqx, wqc,
                                                bqkv_x, bqkv_c, Qb, Kb, VTf);

  flash_attn<<<dim3(9, 48), dim3(512), 0, stream>>>(Qb, Kb, VTf, AX, AC);

  gemm_proj<<<dim3(216), dim3(512), 0, stream>>>(AX, AC, wpx, wpc,
                                                 bproj_x, bproj_c, out);
}